// Round 12
// baseline (59.597 us; speedup 1.0000x reference)
//
#include <hip/hip_runtime.h>

#define HH    1024
#define WW    1024
#define KS    15
#define PAD   7
#define CELL  256
#define BX    64            // x-width per block (4 waves x 16)
#define STRIP 128           // output rows per block
#define TROWS (STRIP + 2*PAD)   // 142
#define TCOLS 80            // staged halves per row (160B rows)
#define NJP   (STRIP / 16)  // 8 row-patches
#define NGRP  (TROWS * 20)  // 2840 float4 groups
#define NPRO  5             // prologue chunks (256 groups each)
#define AWS_CELL_BYTES (KS * 1024)   // 15 fragments x 1KB

typedef _Float16     f16x8 __attribute__((ext_vector_type(8)));
typedef _Float16     f16x4 __attribute__((ext_vector_type(4)));
typedef float        f32x4 __attribute__((ext_vector_type(4)));
typedef unsigned int u32x4 __attribute__((ext_vector_type(4)));

// ---- prep: materialize normalized Toeplitz A fragments per cell into d_ws ----
__global__ __launch_bounds__(256) void pb_prep_kernel(
    const float* __restrict__ kern, unsigned int* __restrict__ aws)
{
    const int cell = blockIdx.x;           // cj*4+ci
    const int tid  = threadIdx.x;
    const int lane = tid & 63;
    const float* kp = kern + cell * (KS * KS);

    float s = 0.f;
    #pragma unroll
    for (int i = 0; i < 4; ++i) {
        int t = lane + 64 * i;
        s += (t < KS * KS) ? kp[t] : 0.f;
    }
    #pragma unroll
    for (int m = 1; m < 64; m <<= 1) s += __shfl_xor(s, m, 64);
    const float inv = 1.0f / (s + 1e-12f);

    const int i  = tid >> 4;               // x-position (A row)
    const int k2 = tid & 15;               // half-pair index
    unsigned int* wp = aws + cell * (AWS_CELL_BYTES / 4) + tid;

    for (int dy = 0; dy < KS; ++dy) {
        float v0 = 0.f, v1 = 0.f;
        int dx0 = 2 * k2 - i - 1;          // A[i][k] = kh[k-i-1]
        int dx1 = dx0 + 1;
        if (dx0 >= 0 && dx0 < KS) v0 = kp[dy * KS + dx0] * inv;
        if (dx1 >= 0 && dx1 < KS) v1 = kp[dy * KS + dx1] * inv;
        f16x4 h; h[0] = (_Float16)v0; h[1] = (_Float16)v1; h[2] = 0; h[3] = 0;
        unsigned long long u = __builtin_bit_cast(unsigned long long, h);
        wp[dy * 256] = (unsigned int)u;
    }
}

// ---- main: R11 pipeline, register-trimmed for 5 waves/SIMD ----
// R11 steady state: 52 VGPR + 60 AGPR(af) + 8 acc ~= 120 regs -> 4 waves/SIMD,
// occupancy 37%, all pipes <40% (latency-bound). Trim: pin only af[0..9]
// (40 regs), stream af[10..14] per patch (5 L1-hot coalesced loads, consumed
// FIRST in the dy loop so transients die early); 1-group/thread chunks.
// Target <=102 regs via __launch_bounds__(256,5). Spill tripwire: WRITE>105MB.
__global__ __launch_bounds__(256, 5) void pb_mfma_kernel(
    const float* __restrict__ x,
    const unsigned int* __restrict__ aws,
    float* __restrict__ out)
{
    __shared__ __align__(16) _Float16 s_tile[TROWS * TCOLS];   // 22720 B

    const int tid  = threadIdx.x;
    const int lane = tid & 63;
    const int w    = tid >> 6;           // wave id: x sub-block
    const int g    = lane >> 4;          // k-group 0..3
    const int cc   = lane & 15;          // A-row / B-col index

    const int bx0   = blockIdx.x * BX;
    const int ci    = blockIdx.x >> 2;   // cell col
    const int strip = blockIdx.y & 1;
    const int cj    = blockIdx.y >> 1;   // cell row
    const int bc    = blockIdx.z;        // plane (b*c)

    const int cellx0 = ci * CELL;
    const int celly0 = cj * CELL, celly1 = celly0 + CELL - 1;
    const int sy0    = celly0 + strip * STRIP;

    const float* plane = x + (size_t)bc * HH * WW;

    // ---- A fragment table pointer (prep layout, R8-proven) ----
    const u32x4* ap = (const u32x4*)(aws + (cj * 4 + ci) * (AWS_CELL_BYTES / 4))
                      + cc * 4 + g;      // + dy*64 per fragment

    // pinned af[0..9] (40 regs)
    u32x4 af[10];
    #pragma unroll
    for (int dy = 0; dy < 10; ++dy) af[dy] = ap[dy * 64];
    #pragma unroll
    for (int dy = 0; dy < 10; ++dy) asm volatile("" : "+v"(af[dy]));

    // ---- staging helpers (clamped-aligned float4 + edge broadcast selects) ----
    auto group_addr = [&](int idx) -> const float* {
        int row  = idx / 20;
        int c4   = idx - row * 20;
        int gy   = min(max(sy0 - PAD + row, celly0), celly1);
        int gx0  = bx0 - 8 + 4 * c4;
        int gx0c = min(max(gx0, cellx0), cellx0 + CELL - 4);
        return plane + (size_t)gy * WW + gx0c;
    };
    auto write_group = [&](int idx, float4 v) {
        int row = idx / 20;
        int c4  = idx - row * 20;
        int gx0 = bx0 - 8 + 4 * c4;
        bool lo = gx0 <  cellx0;
        bool hi = gx0 >  cellx0 + CELL - 4;
        float e0 = hi ? v.w : v.x;
        float e1 = lo ? v.x : (hi ? v.w : v.y);
        float e2 = lo ? v.x : (hi ? v.w : v.z);
        float e3 = lo ? v.x : v.w;
        f16x4 h;
        h[0] = (_Float16)e0; h[1] = (_Float16)e1;
        h[2] = (_Float16)e2; h[3] = (_Float16)e3;
        *(f16x4*)(s_tile + row * TCOLS + 4 * c4) = h;
    };

    // ---- prologue: chunks 0..4 (groups 0..1279, rows 0..63) ----
    {
        float4 p[NPRO];
        #pragma unroll
        for (int c = 0; c < NPRO; ++c)
            p[c] = *(const float4*)group_addr(c * 256 + tid);
        #pragma unroll
        for (int c = 0; c < NPRO; ++c)
            write_group(c * 256 + tid, p[c]);
    }
    __syncthreads();

    // ---- pipelined main loop: 8 patches; chunk 5+jp issued during patch jp ----
    // Landed-vs-needed check: after patch jp's barrier, groups < min(256*(6+jp),
    // NGRP) are visible; patch jp+1 reads rows <= 16(jp+1)+29 -> groups <
    // (16jp+46)*20. 256*(6+jp) >= 320jp+920 for all jp<=7 (chunk 11 lands at
    // jp=6, covering patch 7's full demand of 2840). Verified per-jp.
    const _Float16* bbase = s_tile + cc * TCOLS + w * 16 + g * 8;
    float* oplane = out + (size_t)bc * HH * WW;

    #pragma unroll
    for (int jp = 0; jp < NJP; ++jp) {
        // stream af[10..14] (same address every patch -> L1-hot)
        u32x4 sa0 = ap[10 * 64];
        u32x4 sa1 = ap[11 * 64];
        u32x4 sa2 = ap[12 * 64];
        u32x4 sa3 = ap[13 * 64];
        u32x4 sa4 = ap[14 * 64];

        // issue next staging chunk (latency hides under the MFMAs below)
        float4 nv = {0.f, 0.f, 0.f, 0.f};
        int   gidx = (NPRO + jp) * 256 + tid;
        bool  hn   = (jp < NJP - 1) && (gidx < NGRP);
        if (hn) nv = *(const float4*)group_addr(gidx);

        f32x4 acc0 = {0.f, 0.f, 0.f, 0.f};
        f32x4 acc1 = {0.f, 0.f, 0.f, 0.f};

        // streamed dys first (transients die early)
        {
            f16x8 b10 = *(const f16x8*)(bbase + (16 * jp + 10) * TCOLS);
            f16x8 b11 = *(const f16x8*)(bbase + (16 * jp + 11) * TCOLS);
            f16x8 b12 = *(const f16x8*)(bbase + (16 * jp + 12) * TCOLS);
            f16x8 b13 = *(const f16x8*)(bbase + (16 * jp + 13) * TCOLS);
            f16x8 b14 = *(const f16x8*)(bbase + (16 * jp + 14) * TCOLS);
            acc0 = __builtin_amdgcn_mfma_f32_16x16x32_f16(__builtin_bit_cast(f16x8, sa0), b10, acc0, 0, 0, 0);
            acc1 = __builtin_amdgcn_mfma_f32_16x16x32_f16(__builtin_bit_cast(f16x8, sa1), b11, acc1, 0, 0, 0);
            acc0 = __builtin_amdgcn_mfma_f32_16x16x32_f16(__builtin_bit_cast(f16x8, sa2), b12, acc0, 0, 0, 0);
            acc1 = __builtin_amdgcn_mfma_f32_16x16x32_f16(__builtin_bit_cast(f16x8, sa3), b13, acc1, 0, 0, 0);
            acc0 = __builtin_amdgcn_mfma_f32_16x16x32_f16(__builtin_bit_cast(f16x8, sa4), b14, acc0, 0, 0, 0);
        }
        // pinned dys
        #pragma unroll
        for (int dy = 0; dy < 10; ++dy) {
            f16x8 b = *(const f16x8*)(bbase + (16 * jp + dy) * TCOLS);
            if (dy & 1)
                acc1 = __builtin_amdgcn_mfma_f32_16x16x32_f16(
                           __builtin_bit_cast(f16x8, af[dy]), b, acc1, 0, 0, 0);
            else
                acc0 = __builtin_amdgcn_mfma_f32_16x16x32_f16(
                           __builtin_bit_cast(f16x8, af[dy]), b, acc0, 0, 0, 0);
        }

        f32x4 r = acc0 + acc1;
        // D: col=lane&15 (image row), row=4*(lane>>4)+e (x position)
        float* op = oplane + (size_t)(sy0 + 16 * jp + cc) * WW + bx0 + 16 * w + 4 * g;
        *(f32x4*)op = r;

        // land the staged chunk and publish to next iteration
        if (hn) write_group(gidx, nv);
        __syncthreads();
    }
}

extern "C" void kernel_launch(void* const* d_in, const int* in_sizes, int n_in,
                              void* d_out, int out_size, void* d_ws, size_t ws_size,
                              hipStream_t stream) {
    (void)in_sizes; (void)n_in; (void)ws_size; (void)out_size;
    const float* x    = (const float*)d_in[0];
    const float* kern = (const float*)d_in[1];
    float* out        = (float*)d_out;
    unsigned int* aws = (unsigned int*)d_ws;   // 16 cells x 15 KiB = 240 KiB

    pb_prep_kernel<<<16, 256, 0, stream>>>(kern, aws);
    dim3 grid(WW / BX, 8, 8 * 3);   // 16 x-strips, 8 y-strips, 24 planes
    pb_mfma_kernel<<<grid, 256, 0, stream>>>(x, aws, out);
}

// Round 13
// 57.684 us; speedup vs baseline: 1.0332x; 1.0332x over previous
//
#include <hip/hip_runtime.h>

#define HH    1024
#define WW    1024
#define KS    15
#define PAD   7
#define CELL  256
#define BX    64            // x-width per block (4 waves x 16)
#define STRIP 128           // output rows per block
#define TROWS (STRIP + 2*PAD)   // 142
#define TCOLS 80            // staged halves per row (160B rows)
#define NJP   (STRIP / 16)  // 8 row-patches
#define NGRP  (TROWS * 20)  // 2840 float4 groups
#define CGRP  320           // groups per 16-row chunk
#define NCHUNK 9            // 8 full chunks + 280-group tail chunk
#define AWS_CELL_BYTES (KS * 1024)   // 15 fragments x 1KB

typedef _Float16     f16x8 __attribute__((ext_vector_type(8)));
typedef _Float16     f16x4 __attribute__((ext_vector_type(4)));
typedef float        f32x4 __attribute__((ext_vector_type(4)));
typedef unsigned int u32x4 __attribute__((ext_vector_type(4)));

// Workgroup barrier WITHOUT vmcnt(0) drain: LDS ordering only.
// __syncthreads() lowers to s_waitcnt vmcnt(0) lgkmcnt(0); s_barrier — the
// vmcnt(0) forces every wave to drain its output store + prefetch loads every
// patch (~300-900 cyc exposed, 8x/block). ds_write of staged data still gets
// its precise vmcnt wait from the register dependency; LDS visibility needs
// only lgkmcnt(0).
static __device__ __forceinline__ void light_barrier() {
    asm volatile("s_waitcnt lgkmcnt(0)\n\ts_barrier" ::: "memory");
}

// ---- prep: materialize normalized Toeplitz A fragments per cell into d_ws ----
__global__ __launch_bounds__(256) void pb_prep_kernel(
    const float* __restrict__ kern, unsigned int* __restrict__ aws)
{
    const int cell = blockIdx.x;           // cj*4+ci
    const int tid  = threadIdx.x;
    const int lane = tid & 63;
    const float* kp = kern + cell * (KS * KS);

    float s = 0.f;
    #pragma unroll
    for (int i = 0; i < 4; ++i) {
        int t = lane + 64 * i;
        s += (t < KS * KS) ? kp[t] : 0.f;
    }
    #pragma unroll
    for (int m = 1; m < 64; m <<= 1) s += __shfl_xor(s, m, 64);
    const float inv = 1.0f / (s + 1e-12f);

    const int i  = tid >> 4;               // x-position (A row)
    const int k2 = tid & 15;               // half-pair index
    unsigned int* wp = aws + cell * (AWS_CELL_BYTES / 4) + tid;

    for (int dy = 0; dy < KS; ++dy) {
        float v0 = 0.f, v1 = 0.f;
        int dx0 = 2 * k2 - i - 1;          // A[i][k] = kh[k-i-1]
        int dx1 = dx0 + 1;
        if (dx0 >= 0 && dx0 < KS) v0 = kp[dy * KS + dx0] * inv;
        if (dx1 >= 0 && dx1 < KS) v1 = kp[dy * KS + dx1] * inv;
        f16x4 h; h[0] = (_Float16)v0; h[1] = (_Float16)v1; h[2] = 0; h[3] = 0;
        unsigned long long u = __builtin_bit_cast(unsigned long long, h);
        wp[dy * 256] = (unsigned int)u;
    }
}

// ---- main: R11 structure + light barriers + depth-2 chunk prefetch ----
// Schedule: prologue stages ch0-1, issues ch2; iter jp issues ch jp+3,
// computes patch jp (reads ch jp..jp+1, disjoint from ch jp+2 write),
// writes ch jp+2 (loaded LAST iter -> full-iteration latency cover),
// light-barrier. In-flight: <=2 chunks = 16 VGPRs (R10's 48-reg batch
// spilled; this stays bounded).
__global__ __launch_bounds__(256, 4) void pb_mfma_kernel(
    const float* __restrict__ x,
    const unsigned int* __restrict__ aws,
    float* __restrict__ out)
{
    __shared__ __align__(16) _Float16 s_tile[TROWS * TCOLS];   // 22720 B

    const int tid  = threadIdx.x;
    const int lane = tid & 63;
    const int w    = tid >> 6;           // wave id: x sub-block
    const int g    = lane >> 4;          // k-group 0..3
    const int cc   = lane & 15;          // A-row / B-col index

    const int bx0   = blockIdx.x * BX;
    const int ci    = blockIdx.x >> 2;   // cell col
    const int strip = blockIdx.y & 1;
    const int cj    = blockIdx.y >> 1;   // cell row
    const int bc    = blockIdx.z;        // plane (b*c)

    const int cellx0 = ci * CELL;
    const int celly0 = cj * CELL, celly1 = celly0 + CELL - 1;
    const int sy0    = celly0 + strip * STRIP;

    const float* plane = x + (size_t)bc * HH * WW;

    // ---- A fragments: 15 coalesced dwordx4 loads, pinned resident (R8) ----
    const u32x4* ap = (const u32x4*)(aws + (cj * 4 + ci) * (AWS_CELL_BYTES / 4))
                      + cc * 4 + g;
    u32x4 af[KS];
    #pragma unroll
    for (int dy = 0; dy < KS; ++dy) af[dy] = ap[dy * 64];
    #pragma unroll
    for (int dy = 0; dy < KS; ++dy) asm volatile("" : "+v"(af[dy]));

    // ---- staging helpers (clamped-aligned float4 + edge broadcast selects) ----
    auto group_addr = [&](int idx) -> const float* {
        int row  = idx / 20;
        int c4   = idx - row * 20;
        int gy   = min(max(sy0 - PAD + row, celly0), celly1);
        int gx0  = bx0 - 8 + 4 * c4;
        int gx0c = min(max(gx0, cellx0), cellx0 + CELL - 4);
        return plane + (size_t)gy * WW + gx0c;
    };
    auto write_group = [&](int idx, float4 v) {
        int row = idx / 20;
        int c4  = idx - row * 20;
        int gx0 = bx0 - 8 + 4 * c4;
        bool lo = gx0 <  cellx0;
        bool hi = gx0 >  cellx0 + CELL - 4;
        float e0 = hi ? v.w : v.x;
        float e1 = lo ? v.x : (hi ? v.w : v.y);
        float e2 = lo ? v.x : (hi ? v.w : v.z);
        float e3 = lo ? v.x : v.w;
        f16x4 h;
        h[0] = (_Float16)e0; h[1] = (_Float16)e1;
        h[2] = (_Float16)e2; h[3] = (_Float16)e3;
        *(f16x4*)(s_tile + row * TCOLS + 4 * c4) = h;
    };
    auto issue_chunk = [&](int c, float4& v0, float4& v1, bool& h0, bool& h1) {
        int base = c * CGRP;
        int ng   = min(CGRP, NGRP - base);
        h0 = tid < ng;
        h1 = 256 + tid < ng;
        if (h0) v0 = *(const float4*)group_addr(base + tid);
        if (h1) v1 = *(const float4*)group_addr(base + 256 + tid);
    };
    auto write_chunk = [&](int c, float4 v0, float4 v1, bool h0, bool h1) {
        int base = c * CGRP;
        if (h0) write_group(base + tid, v0);
        if (h1) write_group(base + 256 + tid, v1);
    };

    // ---- prologue: stage chunks 0,1; issue chunk 2 (pending) ----
    float4 p0, p1; bool hp0, hp1;
    {
        float4 a0, a1, b0, b1; bool ha0, ha1, hb0, hb1;
        issue_chunk(0, a0, a1, ha0, ha1);
        issue_chunk(1, b0, b1, hb0, hb1);
        write_chunk(0, a0, a1, ha0, ha1);
        write_chunk(1, b0, b1, hb0, hb1);
        issue_chunk(2, p0, p1, hp0, hp1);
    }
    light_barrier();

    // ---- pipelined main loop: 8 patches ----
    const _Float16* bbase = s_tile + cc * TCOLS + w * 16 + g * 8;
    float* oplane = out + (size_t)bc * HH * WW;

    #pragma unroll
    for (int jp = 0; jp < NJP; ++jp) {
        // issue chunk jp+3 (written NEXT iter -> full-iter latency cover)
        float4 n0 = {0,0,0,0}, n1 = {0,0,0,0}; bool hn0 = false, hn1 = false;
        if (jp + 3 < NCHUNK) issue_chunk(jp + 3, n0, n1, hn0, hn1);

        // compute patch jp (reads staged rows 16jp..16jp+30: chunks jp, jp+1)
        f32x4 acc0 = {0.f, 0.f, 0.f, 0.f};
        f32x4 acc1 = {0.f, 0.f, 0.f, 0.f};
        #pragma unroll
        for (int dy = 0; dy < KS; ++dy) {
            f16x8 b = *(const f16x8*)(bbase + (16 * jp + dy) * TCOLS);
            if (dy & 1)
                acc1 = __builtin_amdgcn_mfma_f32_16x16x32_f16(
                           __builtin_bit_cast(f16x8, af[dy]), b, acc1, 0, 0, 0);
            else
                acc0 = __builtin_amdgcn_mfma_f32_16x16x32_f16(
                           __builtin_bit_cast(f16x8, af[dy]), b, acc0, 0, 0, 0);
        }
        f32x4 r = acc0 + acc1;
        // D: col=lane&15 (image row), row=4*(lane>>4)+e (x position)
        float* op = oplane + (size_t)(sy0 + 16 * jp + cc) * WW + bx0 + 16 * w + 4 * g;
        *(f32x4*)op = r;   // store rides across light barriers, no drain

        // land pending chunk jp+2 (disjoint from patch jp's reads)
        if (jp + 2 < NCHUNK) write_chunk(jp + 2, p0, p1, hp0, hp1);
        light_barrier();

        p0 = n0; p1 = n1; hp0 = hn0; hp1 = hn1;
    }
}

extern "C" void kernel_launch(void* const* d_in, const int* in_sizes, int n_in,
                              void* d_out, int out_size, void* d_ws, size_t ws_size,
                              hipStream_t stream) {
    (void)in_sizes; (void)n_in; (void)ws_size; (void)out_size;
    const float* x    = (const float*)d_in[0];
    const float* kern = (const float*)d_in[1];
    float* out        = (float*)d_out;
    unsigned int* aws = (unsigned int*)d_ws;   // 16 cells x 15 KiB = 240 KiB

    pb_prep_kernel<<<16, 256, 0, stream>>>(kern, aws);
    dim3 grid(WW / BX, 8, 8 * 3);   // 16 x-strips, 8 y-strips, 24 planes
    pb_mfma_kernel<<<grid, 256, 0, stream>>>(x, aws, out);
}